// Round 7
// baseline (181.897 us; speedup 1.0000x reference)
//
#include <hip/hip_runtime.h>
#include <hip/hip_bf16.h>

typedef short s16x8 __attribute__((ext_vector_type(8)));
typedef short s16x4 __attribute__((ext_vector_type(4)));
typedef float f32x4 __attribute__((ext_vector_type(4)));
typedef float f32x16 __attribute__((ext_vector_type(16)));
typedef unsigned int u32x4 __attribute__((ext_vector_type(4)));

#define S_LEN 2048
#define DMODEL 1024
#define NHEAD 16
#define HDIM 64
#define OUT_ELEMS 4194304   // B*S*D
#define HEAD_ELEMS 4194304  // B*H*S*HD
#define SCALE_LOG2 0.1803368801111204f  // 0.125 * log2(e), folded into Q

__device__ inline short f2bf(float f) {
  __hip_bfloat16 h = __float2bfloat16(f);  // RNE
  return __builtin_bit_cast(short, h);
}

__device__ inline f32x4 mfma16(s16x8 a, s16x8 b, f32x4 c) {
  return __builtin_amdgcn_mfma_f32_16x16x32_bf16(a, b, c, 0, 0, 0);
}
__device__ inline f32x16 mfma32(s16x8 a, s16x8 b, f32x16 c) {
  return __builtin_amdgcn_mfma_f32_32x32x16_bf16(a, b, c, 0, 0, 0);
}

// pack two f32 -> one dword of 2 bf16 (hw RNE): src0 -> [15:0], src1 -> [31:16]
__device__ inline unsigned int cvt_pk_bf16(float lo, float hi) {
  unsigned int d;
  asm("v_cvt_pk_bf16_f32 %0, %1, %2" : "=v"(d) : "v"(lo), "v"(hi));
  return d;
}

// ---- convert+transpose: in [R][C] f32 -> out [C][R] bf16 ----
__global__ __launch_bounds__(256) void transpose_cvt(
    const float* __restrict__ in, short* __restrict__ out, int R, int C) {
  int g = blockIdx.x * 256 + threadIdx.x;
  int c = g % C;
  int r0 = (g / C) * 8;
  s16x8 v;
#pragma unroll
  for (int j = 0; j < 8; j++) v[j] = f2bf(in[(size_t)(r0 + j) * C + c]);
  *(s16x8*)&out[(size_t)c * R + r0] = v;
}

// ---- GEMM: C = A[M,K] * Bt[N,K]^T + bias. ----
template <int MODE, bool AF32>
__global__ __launch_bounds__(256) void gemm_bt(
    const void* __restrict__ Araw, const short* __restrict__ Bt,
    const float* __restrict__ bias, short* __restrict__ Ob0,
    float* __restrict__ Of, short* __restrict__ VtOut,
    short* __restrict__ KwOut, int M, int N, int K) {
  __shared__ short As[128][40];
  __shared__ short Bs[128][40];
  const int t = threadIdx.x;
  const int lane = t & 63;
  const int wid = t >> 6;
  const int wr = wid >> 1, wc = wid & 1;
  const int l16 = lane & 15, lg = lane >> 4;
  const int mbase = blockIdx.y * 128;
  const int nbase = blockIdx.x * 128;

  f32x4 acc[4][4];
#pragma unroll
  for (int m = 0; m < 4; m++)
#pragma unroll
    for (int n = 0; n < 4; n++) acc[m][n] = (f32x4){0.f, 0.f, 0.f, 0.f};

  const int srow = t >> 2;
  const int skc = (t & 3) * 8;

  for (int k0 = 0; k0 < K; k0 += 32) {
    s16x8 a0, a1;
    if constexpr (AF32) {
      const float* Af = (const float*)Araw;
      const float* p0 = &Af[(size_t)(mbase + srow) * K + k0 + skc];
      const float* p1 = &Af[(size_t)(mbase + srow + 64) * K + k0 + skc];
      f32x4 x00 = *(const f32x4*)p0, x01 = *(const f32x4*)(p0 + 4);
      f32x4 x10 = *(const f32x4*)p1, x11 = *(const f32x4*)(p1 + 4);
#pragma unroll
      for (int j = 0; j < 4; j++) {
        a0[j] = f2bf(x00[j]); a0[4 + j] = f2bf(x01[j]);
        a1[j] = f2bf(x10[j]); a1[4 + j] = f2bf(x11[j]);
      }
    } else {
      const short* Ab = (const short*)Araw;
      a0 = *(const s16x8*)&Ab[(size_t)(mbase + srow) * K + k0 + skc];
      a1 = *(const s16x8*)&Ab[(size_t)(mbase + srow + 64) * K + k0 + skc];
    }
    s16x8 b0 = *(const s16x8*)&Bt[(size_t)(nbase + srow) * K + k0 + skc];
    s16x8 b1 = *(const s16x8*)&Bt[(size_t)(nbase + srow + 64) * K + k0 + skc];
    __syncthreads();
    *(s16x8*)&As[srow][skc] = a0;
    *(s16x8*)&As[srow + 64][skc] = a1;
    *(s16x8*)&Bs[srow][skc] = b0;
    *(s16x8*)&Bs[srow + 64][skc] = b1;
    __syncthreads();
    s16x8 af[4], bfr[4];
#pragma unroll
    for (int m = 0; m < 4; m++)
      af[m] = *(const s16x8*)&As[wr * 64 + m * 16 + l16][lg * 8];
#pragma unroll
    for (int n = 0; n < 4; n++)
      bfr[n] = *(const s16x8*)&Bs[wc * 64 + n * 16 + l16][lg * 8];
#pragma unroll
    for (int m = 0; m < 4; m++)
#pragma unroll
      for (int n = 0; n < 4; n++)
        acc[m][n] = mfma16(af[m], bfr[n], acc[m][n]);
  }

#pragma unroll
  for (int m = 0; m < 4; m++) {
#pragma unroll
    for (int n = 0; n < 4; n++) {
      int gcol = nbase + wc * 64 + n * 16 + l16;
      float bv = bias[gcol];
      int part = gcol >> 10;
      int cin = gcol & 1023;
      int h = cin >> 6, hd = cin & 63;
      int grow0 = mbase + wr * 64 + m * 16 + lg * 4;
      float vr[4];
#pragma unroll
      for (int r = 0; r < 4; r++) vr[r] = acc[m][n][r] + bv;
      if (MODE == 0) {
        int bb = grow0 >> 11, s0 = grow0 & 2047;
        size_t base = ((size_t)(bb * NHEAD + h) * S_LEN + s0) * HDIM + hd;
        if (part == 0) {
#pragma unroll
          for (int r = 0; r < 4; r++)
            Ob0[base + (size_t)r * HDIM] = f2bf(vr[r] * SCALE_LOG2);
        } else if (part == 1) {
#pragma unroll
          for (int r = 0; r < 4; r++) Of[base + (size_t)r * HDIM] = vr[r];
          if (KwOut) {
#pragma unroll
            for (int r = 0; r < 4; r++)
              KwOut[base + (size_t)r * HDIM] = f2bf(vr[r]);
          }
        } else {
#pragma unroll
          for (int r = 0; r < 4; r++)
            Of[HEAD_ELEMS + base + (size_t)r * HDIM] = vr[r];
          s16x4 pk;
#pragma unroll
          for (int r = 0; r < 4; r++) pk[r] = f2bf(vr[r]);
          *(s16x4*)&VtOut[((size_t)(bb * NHEAD + h) * HDIM + hd) * S_LEN + s0] = pk;
        }
      } else {
#pragma unroll
        for (int r = 0; r < 4; r++) Of[(size_t)(grow0 + r) * N + gcol] = vr[r];
      }
    }
  }
}

// ---- causal flash attention: paired q-tiles (j, 63-j) per block, ----------
// ---- k-split across 4 waves + LDS combine, K prefetch ---------------------
// PV uses sigma-permuted key order so P^T is lane-local (no cross-lane ops):
//   B slot (hi, j) carries key kc*16 + (j<4 ? hi*4+j : 8+hi*4+j-4)
//   matching V^T A-fragments are loaded as two s16x4 chunks per kc.
template <bool KBF16>
__device__ __forceinline__ void attn_body(const short* __restrict__ Q,
                                          const void* __restrict__ Kraw,
                                          const short* __restrict__ Vt,
                                          short* __restrict__ AO) {
  __shared__ float XFER[2][64][37];

  const int p = blockIdx.x;                 // 1024 blocks
  const int xcd = p & 7;
  const int rank = p >> 3;                  // 0..127
  const int bh = (xcd << 2) | (rank >> 5);  // 4 bh per XCD residue class
  const int pr = rank & 31;

  const int tid = threadIdx.x;
  const int w = tid >> 6;
  const int lane = tid & 63;
  const int l32 = lane & 31;
  const int hi = lane >> 5;

  const short* Qb = Q + (size_t)bh * (S_LEN * HDIM);
  const short* Vb = Vt + (size_t)bh * (HDIM * S_LEN);
  const short* Kb16 = (const short*)Kraw + (size_t)bh * (S_LEN * HDIM);
  const float* Kb32 = (const float*)Kraw + (size_t)bh * (S_LEN * HDIM);
  const int b = bh >> 4, h = bh & 15;

#pragma unroll 1
  for (int ph = 0; ph < 2; ph++) {
    const int j = ph ? pr : 63 - pr;   // pair sums to 65 trips -> equal CUs
    const int qb = j * 32;

    s16x8 qf[4];
#pragma unroll
    for (int c = 0; c < 4; c++)
      qf[c] = *(const s16x8*)&Qb[(size_t)(qb + l32) * HDIM + c * 16 + hi * 8];

    f32x16 acc0 = {0.f}, acc1 = {0.f};
    float m = -1e30f, ll = 0.f;

    s16x8 kcur[4];
    if constexpr (KBF16) {
      if (w <= j) {
#pragma unroll
        for (int c = 0; c < 4; c++)
          kcur[c] = *(const s16x8*)&Kb16[(size_t)(w * 32 + l32) * HDIM +
                                         c * 16 + hi * 8];
      }
    }

#pragma unroll 1
    for (int kt = w; kt <= j; kt += 4) {
      const int kb = kt * 32;
      // S^T[key][q] = K . Q^T
      f32x16 S = {0.f};
      if constexpr (KBF16) {
#pragma unroll
        for (int c = 0; c < 4; c++) S = mfma32(kcur[c], qf[c], S);
      } else {
#pragma unroll
        for (int c = 0; c < 4; c++) {
          const float* kr = &Kb32[(size_t)(kb + l32) * HDIM + c * 16 + hi * 8];
          f32x4 k0 = *(const f32x4*)kr, k1 = *(const f32x4*)(kr + 4);
          s16x8 kf;
#pragma unroll
          for (int u = 0; u < 4; u++) {
            kf[u] = f2bf(k0[u]);
            kf[4 + u] = f2bf(k1[u]);
          }
          S = mfma32(kf, qf[c], S);
        }
      }
      // V loads early (latency hides under softmax), sigma-permuted chunks
      const short* vr0 = &Vb[(size_t)l32 * S_LEN + kb + hi * 4];
      const short* vr1 = &Vb[(size_t)(32 + l32) * S_LEN + kb + hi * 4];
      s16x4 c00 = *(const s16x4*)vr0;         // kc0: keys hi*4+0..3
      s16x4 c01 = *(const s16x4*)(vr0 + 8);   // kc0: keys 8+hi*4+0..3
      s16x4 c02 = *(const s16x4*)(vr0 + 16);  // kc1
      s16x4 c03 = *(const s16x4*)(vr0 + 24);
      s16x4 c10 = *(const s16x4*)vr1;
      s16x4 c11 = *(const s16x4*)(vr1 + 8);
      s16x4 c12 = *(const s16x4*)(vr1 + 16);
      s16x4 c13 = *(const s16x4*)(vr1 + 24);
      // prefetch next K tile (hides under softmax+PV)
      if constexpr (KBF16) {
        if (kt + 4 <= j) {
#pragma unroll
          for (int c = 0; c < 4; c++)
            kcur[c] = *(const s16x8*)&Kb16[(size_t)(kb + 128 + l32) * HDIM +
                                           c * 16 + hi * 8];
        }
      }
      // causal mask on diagonal tile
      if (kt == j) {
#pragma unroll
        for (int r = 0; r < 16; r++) {
          int keyl = (r & 3) + 8 * (r >> 2) + 4 * hi;
          S[r] = (keyl <= l32) ? S[r] : -1e30f;
        }
      }
      // tile max: in-lane tree + one cross-half exchange
      float t8[8];
#pragma unroll
      for (int r = 0; r < 8; r++) t8[r] = fmaxf(S[2 * r], S[2 * r + 1]);
      float tmax = fmaxf(fmaxf(fmaxf(t8[0], t8[1]), fmaxf(t8[2], t8[3])),
                         fmaxf(fmaxf(t8[4], t8[5]), fmaxf(t8[6], t8[7])));
      tmax = fmaxf(tmax, __shfl_xor(tmax, 32));
      // defer-max rescale
      if (!__all(tmax <= m + 11.0f)) {
        float mn = fmaxf(m, tmax);
        float alpha = __builtin_amdgcn_exp2f(m - mn);
        ll *= alpha;
#pragma unroll
        for (int r = 0; r < 16; r++) {
          acc0[r] *= alpha;
          acc1[r] *= alpha;
        }
        m = mn;
      }
#pragma unroll
      for (int r = 0; r < 16; r++) S[r] = __builtin_amdgcn_exp2f(S[r] - m);
      // tile sum: in-lane tree + one cross-half exchange
      float s8[8];
#pragma unroll
      for (int r = 0; r < 8; r++) s8[r] = S[2 * r] + S[2 * r + 1];
      float rs = ((s8[0] + s8[1]) + (s8[2] + s8[3])) +
                 ((s8[4] + s8[5]) + (s8[6] + s8[7]));
      rs += __shfl_xor(rs, 32);
      ll += rs;
      // pack P: W[g] = (S[2g] -> lo, S[2g+1] -> hi); these ARE the B dwords
      u32x4 pb0, pb1;
#pragma unroll
      for (int g = 0; g < 4; g++) pb0[g] = cvt_pk_bf16(S[2 * g], S[2 * g + 1]);
#pragma unroll
      for (int g = 0; g < 4; g++)
        pb1[g] = cvt_pk_bf16(S[8 + 2 * g], S[9 + 2 * g]);
      // PV: O^T[d][q] += V^T . P^T (sigma-permuted k-order, lane-local P)
      {
        s16x8 pb = __builtin_bit_cast(s16x8, pb0);
        s16x8 va0 = __builtin_shufflevector(c00, c01, 0, 1, 2, 3, 4, 5, 6, 7);
        s16x8 va1 = __builtin_shufflevector(c10, c11, 0, 1, 2, 3, 4, 5, 6, 7);
        acc0 = mfma32(va0, pb, acc0);
        acc1 = mfma32(va1, pb, acc1);
      }
      {
        s16x8 pb = __builtin_bit_cast(s16x8, pb1);
        s16x8 va0 = __builtin_shufflevector(c02, c03, 0, 1, 2, 3, 4, 5, 6, 7);
        s16x8 va1 = __builtin_shufflevector(c12, c13, 0, 1, 2, 3, 4, 5, 6, 7);
        acc0 = mfma32(va0, pb, acc0);
        acc1 = mfma32(va1, pb, acc1);
      }
    }

    // ---- combine the 4 per-wave partials (tree merge via LDS) ----
    if (w & 1) {
      float* dst = &XFER[w >> 1][lane][0];
      dst[0] = m; dst[1] = ll;
#pragma unroll
      for (int r = 0; r < 16; r++) { dst[2 + r] = acc0[r]; dst[18 + r] = acc1[r]; }
    }
    __syncthreads();
    if (!(w & 1)) {
      const float* src = &XFER[w >> 1][lane][0];
      float m2 = src[0], l2 = src[1];
      float M = fmaxf(m, m2);
      float a1 = __builtin_amdgcn_exp2f(m - M);
      float a2 = __builtin_amdgcn_exp2f(m2 - M);
      ll = ll * a1 + l2 * a2;
#pragma unroll
      for (int r = 0; r < 16; r++) {
        acc0[r] = acc0[r] * a1 + src[2 + r] * a2;
        acc1[r] = acc1[r] * a1 + src[18 + r] * a2;
      }
      m = M;
    }
    __syncthreads();
    if (w == 2) {
      float* dst = &XFER[0][lane][0];
      dst[0] = m; dst[1] = ll;
#pragma unroll
      for (int r = 0; r < 16; r++) { dst[2 + r] = acc0[r]; dst[18 + r] = acc1[r]; }
    }
    __syncthreads();
    if (w == 0) {
      const float* src = &XFER[0][lane][0];
      float m2 = src[0], l2 = src[1];
      float M = fmaxf(m, m2);
      float a1 = __builtin_amdgcn_exp2f(m - M);
      float a2 = __builtin_amdgcn_exp2f(m2 - M);
      ll = ll * a1 + l2 * a2;
#pragma unroll
      for (int r = 0; r < 16; r++) {
        acc0[r] = acc0[r] * a1 + src[2 + r] * a2;
        acc1[r] = acc1[r] * a1 + src[18 + r] * a2;
      }
      float inv = 1.f / ll;
      size_t rowbase = ((size_t)(b * S_LEN + qb + l32)) * DMODEL + h * HDIM;
#pragma unroll
      for (int g = 0; g < 4; g++) {
        s16x4 o0, o1;
#pragma unroll
        for (int u = 0; u < 4; u++) {
          o0[u] = f2bf(acc0[4 * g + u] * inv);
          o1[u] = f2bf(acc1[4 * g + u] * inv);
        }
        *(s16x4*)&AO[rowbase + 8 * g + 4 * hi] = o0;
        *(s16x4*)&AO[rowbase + 32 + 8 * g + 4 * hi] = o1;
      }
    }
    __syncthreads();  // protect XFER reuse across phases
  }
}

__global__ __launch_bounds__(256, 4) void attn_fwd_kbf16(
    const short* __restrict__ Q, const short* __restrict__ K,
    const short* __restrict__ Vt, short* __restrict__ AO) {
  attn_body<true>(Q, K, Vt, AO);
}
__global__ __launch_bounds__(256, 4) void attn_fwd_kf32(
    const short* __restrict__ Q, const float* __restrict__ K,
    const short* __restrict__ Vt, short* __restrict__ AO) {
  attn_body<false>(Q, K, Vt, AO);
}

extern "C" void kernel_launch(void* const* d_in, const int* in_sizes, int n_in,
                              void* d_out, int out_size, void* d_ws,
                              size_t ws_size, hipStream_t stream) {
  const float* x = (const float*)d_in[0];
  const float* w_qkv = (const float*)d_in[1];
  const float* b_qkv = (const float*)d_in[2];
  const float* w_proj = (const float*)d_in[3];
  const float* b_proj = (const float*)d_in[4];
  float* out = (float*)d_out;
  float* presentK = out + OUT_ELEMS;  // f32 [bh][S][64]

  short* ws = (short*)d_ws;
  const bool kbf16 = ws_size >= (size_t)35651584;  // 17,825,792 shorts

  short *Qw, *Vt, *wprojT, *wqkvT, *attnout, *Kw;
  if (kbf16) {
    Qw = ws;                  // 4,194,304
    Kw = ws + 4194304;        // 4,194,304
    Vt = ws + 8388608;        // 4,194,304
    wprojT = ws + 12582912;   // 1,048,576
    wqkvT = ws + 13631488;    // 3,145,728 (dead after QKV gemm)
    attnout = ws + 13631488;  // 4,194,304 (overlays wqkvT)
  } else {
    if (ws_size < (size_t)27262976) return;
    Qw = ws;
    Vt = ws + 4194304;
    wprojT = ws + 8388608;
    wqkvT = ws + 9437184;
    attnout = ws + 9437184;
    Kw = nullptr;
  }

  transpose_cvt<<<dim3(1536), 256, 0, stream>>>(w_qkv, wqkvT, 1024, 3072);
  transpose_cvt<<<dim3(512), 256, 0, stream>>>(w_proj, wprojT, 1024, 1024);
  // QKV projection: Q(pre-scaled)->Qw, K->presentK f32 (+Kw bf16), V->f32+Vt
  gemm_bt<0, true><<<dim3(24, 32), 256, 0, stream>>>(
      x, wqkvT, b_qkv, Qw, presentK, Vt, Kw, 4096, 3072, 1024);
  // causal attention (paired q-tiles, k-split + combine)
  if (kbf16)
    attn_fwd_kbf16<<<dim3(1024), 256, 0, stream>>>(Qw, Kw, Vt, attnout);
  else
    attn_fwd_kf32<<<dim3(1024), 256, 0, stream>>>(Qw, presentK, Vt, attnout);
  // output projection -> f32 out
  gemm_bt<1, false><<<dim3(8, 32), 256, 0, stream>>>(
      attnout, wprojT, b_proj, nullptr, out, nullptr, nullptr, 4096, 1024,
      1024);
}

// Round 8
// 154.981 us; speedup vs baseline: 1.1737x; 1.1737x over previous
//
#include <hip/hip_runtime.h>
#include <hip/hip_bf16.h>

typedef short s16x8 __attribute__((ext_vector_type(8)));
typedef short s16x4 __attribute__((ext_vector_type(4)));
typedef float f32x4 __attribute__((ext_vector_type(4)));
typedef float f32x16 __attribute__((ext_vector_type(16)));
typedef unsigned int u32x4 __attribute__((ext_vector_type(4)));

#define S_LEN 2048
#define DMODEL 1024
#define NHEAD 16
#define HDIM 64
#define OUT_ELEMS 4194304   // B*S*D
#define HEAD_ELEMS 4194304  // B*H*S*HD
#define SCALE_LOG2 0.1803368801111204f  // 0.125 * log2(e), folded into Q

__device__ inline short f2bf(float f) {
  __hip_bfloat16 h = __float2bfloat16(f);  // RNE
  return __builtin_bit_cast(short, h);
}

__device__ inline f32x4 mfma16(s16x8 a, s16x8 b, f32x4 c) {
  return __builtin_amdgcn_mfma_f32_16x16x32_bf16(a, b, c, 0, 0, 0);
}
__device__ inline f32x16 mfma32(s16x8 a, s16x8 b, f32x16 c) {
  return __builtin_amdgcn_mfma_f32_32x32x16_bf16(a, b, c, 0, 0, 0);
}

// ---- convert+transpose: in [R][C] f32 -> out [C][R] bf16 ----
__global__ __launch_bounds__(256) void transpose_cvt(
    const float* __restrict__ in, short* __restrict__ out, int R, int C) {
  int g = blockIdx.x * 256 + threadIdx.x;
  int c = g % C;
  int r0 = (g / C) * 8;
  s16x8 v;
#pragma unroll
  for (int j = 0; j < 8; j++) v[j] = f2bf(in[(size_t)(r0 + j) * C + c]);
  *(s16x8*)&out[(size_t)c * R + r0] = v;
}

// ---- GEMM: C = A[M,K] * Bt[N,K]^T + bias. ----
// MODE 0: QKV scatter: Q(pre-scaled)->Ob0 bf16, K->Of f32 (+KwOut bf16),
//         V->Of f32 + VtOut bf16 transposed with sigma-permuted key order:
//         within each 32-key block, key k -> pos kc*16+hig*8+sec*4+t
//         (kc=k>>4, hig=(k>>2)&1, sec=(k>>3)&1, t=k&3)
// MODE 1: plain f32 row-major store to Of
template <int MODE, bool AF32>
__global__ __launch_bounds__(256) void gemm_bt(
    const void* __restrict__ Araw, const short* __restrict__ Bt,
    const float* __restrict__ bias, short* __restrict__ Ob0,
    float* __restrict__ Of, short* __restrict__ VtOut,
    short* __restrict__ KwOut, int M, int N, int K) {
  __shared__ short As[128][40];
  __shared__ short Bs[128][40];
  const int t = threadIdx.x;
  const int lane = t & 63;
  const int wid = t >> 6;
  const int wr = wid >> 1, wc = wid & 1;
  const int l16 = lane & 15, lg = lane >> 4;
  const int mbase = blockIdx.y * 128;
  const int nbase = blockIdx.x * 128;

  f32x4 acc[4][4];
#pragma unroll
  for (int m = 0; m < 4; m++)
#pragma unroll
    for (int n = 0; n < 4; n++) acc[m][n] = (f32x4){0.f, 0.f, 0.f, 0.f};

  const int srow = t >> 2;
  const int skc = (t & 3) * 8;

  for (int k0 = 0; k0 < K; k0 += 32) {
    s16x8 a0, a1;
    if constexpr (AF32) {
      const float* Af = (const float*)Araw;
      const float* p0 = &Af[(size_t)(mbase + srow) * K + k0 + skc];
      const float* p1 = &Af[(size_t)(mbase + srow + 64) * K + k0 + skc];
      f32x4 x00 = *(const f32x4*)p0, x01 = *(const f32x4*)(p0 + 4);
      f32x4 x10 = *(const f32x4*)p1, x11 = *(const f32x4*)(p1 + 4);
#pragma unroll
      for (int j = 0; j < 4; j++) {
        a0[j] = f2bf(x00[j]); a0[4 + j] = f2bf(x01[j]);
        a1[j] = f2bf(x10[j]); a1[4 + j] = f2bf(x11[j]);
      }
    } else {
      const short* Ab = (const short*)Araw;
      a0 = *(const s16x8*)&Ab[(size_t)(mbase + srow) * K + k0 + skc];
      a1 = *(const s16x8*)&Ab[(size_t)(mbase + srow + 64) * K + k0 + skc];
    }
    s16x8 b0 = *(const s16x8*)&Bt[(size_t)(nbase + srow) * K + k0 + skc];
    s16x8 b1 = *(const s16x8*)&Bt[(size_t)(nbase + srow + 64) * K + k0 + skc];
    __syncthreads();
    *(s16x8*)&As[srow][skc] = a0;
    *(s16x8*)&As[srow + 64][skc] = a1;
    *(s16x8*)&Bs[srow][skc] = b0;
    *(s16x8*)&Bs[srow + 64][skc] = b1;
    __syncthreads();
    s16x8 af[4], bfr[4];
#pragma unroll
    for (int m = 0; m < 4; m++)
      af[m] = *(const s16x8*)&As[wr * 64 + m * 16 + l16][lg * 8];
#pragma unroll
    for (int n = 0; n < 4; n++)
      bfr[n] = *(const s16x8*)&Bs[wc * 64 + n * 16 + l16][lg * 8];
#pragma unroll
    for (int m = 0; m < 4; m++)
#pragma unroll
      for (int n = 0; n < 4; n++)
        acc[m][n] = mfma16(af[m], bfr[n], acc[m][n]);
  }

#pragma unroll
  for (int m = 0; m < 4; m++) {
#pragma unroll
    for (int n = 0; n < 4; n++) {
      int gcol = nbase + wc * 64 + n * 16 + l16;
      float bv = bias[gcol];
      int part = gcol >> 10;
      int cin = gcol & 1023;
      int h = cin >> 6, hd = cin & 63;
      int grow0 = mbase + wr * 64 + m * 16 + lg * 4;
      float vr[4];
#pragma unroll
      for (int r = 0; r < 4; r++) vr[r] = acc[m][n][r] + bv;
      if (MODE == 0) {
        int bb = grow0 >> 11, s0 = grow0 & 2047;
        size_t base = ((size_t)(bb * NHEAD + h) * S_LEN + s0) * HDIM + hd;
        if (part == 0) {
#pragma unroll
          for (int r = 0; r < 4; r++)
            Ob0[base + (size_t)r * HDIM] = f2bf(vr[r] * SCALE_LOG2);
        } else if (part == 1) {
#pragma unroll
          for (int r = 0; r < 4; r++) Of[base + (size_t)r * HDIM] = vr[r];
          if (KwOut) {
#pragma unroll
            for (int r = 0; r < 4; r++)
              KwOut[base + (size_t)r * HDIM] = f2bf(vr[r]);
          }
        } else {
#pragma unroll
          for (int r = 0; r < 4; r++)
            Of[HEAD_ELEMS + base + (size_t)r * HDIM] = vr[r];
          s16x4 pk;
#pragma unroll
          for (int r = 0; r < 4; r++) pk[r] = f2bf(vr[r]);
          // sigma-permuted key position (runs of 4 preserved)
          int w32 = s0 & 31;
          int nw = ((w32 >> 4) << 4) | ((w32 & 4) << 1) | ((w32 & 8) >> 1);
          int sperm = (s0 & ~31) | nw;
          *(s16x4*)&VtOut[((size_t)(bb * NHEAD + h) * HDIM + hd) * S_LEN +
                          sperm] = pk;
        }
      } else {
#pragma unroll
        for (int r = 0; r < 4; r++) Of[(size_t)(grow0 + r) * N + gcol] = vr[r];
      }
    }
  }
}

// ---- causal flash attention: paired q-tiles (j, 63-j) per block, ----------
// ---- k-split across 4 waves + LDS combine, K prefetch ---------------------
// PV uses sigma-permuted key order baked into Vt: B k-slot (hi,j) carries
// key kc*16 + (j<4 ? 4*hi+j : 8+4*hi+j-4); Vt stores keys so each lane's
// A-fragment is one contiguous 16B load.
template <bool KBF16>
__device__ __forceinline__ void attn_body(const short* __restrict__ Q,
                                          const void* __restrict__ Kraw,
                                          const short* __restrict__ Vt,
                                          short* __restrict__ AO) {
  __shared__ float XFER[2][64][37];

  const int p = blockIdx.x;                 // 1024 blocks
  const int xcd = p & 7;
  const int rank = p >> 3;                  // 0..127
  const int bh = (xcd << 2) | (rank >> 5);  // 4 bh per XCD residue class
  const int pr = rank & 31;

  const int tid = threadIdx.x;
  const int w = tid >> 6;
  const int lane = tid & 63;
  const int l32 = lane & 31;
  const int hi = lane >> 5;

  const short* Qb = Q + (size_t)bh * (S_LEN * HDIM);
  const short* Vb = Vt + (size_t)bh * (HDIM * S_LEN);
  const short* Kb16 = (const short*)Kraw + (size_t)bh * (S_LEN * HDIM);
  const float* Kb32 = (const float*)Kraw + (size_t)bh * (S_LEN * HDIM);
  const int b = bh >> 4, h = bh & 15;

#pragma unroll 1
  for (int ph = 0; ph < 2; ph++) {
    const int j = ph ? pr : 63 - pr;   // pair sums to 65 trips -> equal CUs
    const int qb = j * 32;

    s16x8 qf[4];
#pragma unroll
    for (int c = 0; c < 4; c++)
      qf[c] = *(const s16x8*)&Qb[(size_t)(qb + l32) * HDIM + c * 16 + hi * 8];

    f32x16 acc0 = {0.f}, acc1 = {0.f};
    float m = -1e30f, ll = 0.f;

    s16x8 kcur[4];
    if constexpr (KBF16) {
      if (w <= j) {
#pragma unroll
        for (int c = 0; c < 4; c++)
          kcur[c] = *(const s16x8*)&Kb16[(size_t)(w * 32 + l32) * HDIM +
                                         c * 16 + hi * 8];
      }
    }

#pragma unroll 1
    for (int kt = w; kt <= j; kt += 4) {
      const int kb = kt * 32;
      // S^T[key][q] = K . Q^T
      f32x16 S = {0.f};
      if constexpr (KBF16) {
#pragma unroll
        for (int c = 0; c < 4; c++) S = mfma32(kcur[c], qf[c], S);
      } else {
#pragma unroll
        for (int c = 0; c < 4; c++) {
          const float* kr = &Kb32[(size_t)(kb + l32) * HDIM + c * 16 + hi * 8];
          f32x4 k0 = *(const f32x4*)kr, k1 = *(const f32x4*)(kr + 4);
          s16x8 kf;
#pragma unroll
          for (int u = 0; u < 4; u++) {
            kf[u] = f2bf(k0[u]);
            kf[4 + u] = f2bf(k1[u]);
          }
          S = mfma32(kf, qf[c], S);
        }
      }
      // V loads early (latency hides under softmax); contiguous 16B frags
      const short* vr0 = &Vb[(size_t)l32 * S_LEN + kb + hi * 8];
      const short* vr1 = &Vb[(size_t)(32 + l32) * S_LEN + kb + hi * 8];
      s16x8 va00 = *(const s16x8*)vr0;         // kc0, dims l32
      s16x8 va01 = *(const s16x8*)(vr0 + 16);  // kc1
      s16x8 va10 = *(const s16x8*)vr1;         // kc0, dims 32+l32
      s16x8 va11 = *(const s16x8*)(vr1 + 16);  // kc1
      // prefetch next K tile (hides under softmax+PV)
      if constexpr (KBF16) {
        if (kt + 4 <= j) {
#pragma unroll
          for (int c = 0; c < 4; c++)
            kcur[c] = *(const s16x8*)&Kb16[(size_t)(kb + 128 + l32) * HDIM +
                                           c * 16 + hi * 8];
        }
      }
      // causal mask on diagonal tile
      if (kt == j) {
#pragma unroll
        for (int r = 0; r < 16; r++) {
          int keyl = (r & 3) + 8 * (r >> 2) + 4 * hi;
          S[r] = (keyl <= l32) ? S[r] : -1e30f;
        }
      }
      // tile max: in-lane tree + one cross-half exchange
      float t8[8];
#pragma unroll
      for (int r = 0; r < 8; r++) t8[r] = fmaxf(S[2 * r], S[2 * r + 1]);
      float tmax = fmaxf(fmaxf(fmaxf(t8[0], t8[1]), fmaxf(t8[2], t8[3])),
                         fmaxf(fmaxf(t8[4], t8[5]), fmaxf(t8[6], t8[7])));
      tmax = fmaxf(tmax, __shfl_xor(tmax, 32));
      // defer-max rescale
      if (!__all(tmax <= m + 11.0f)) {
        float mn = fmaxf(m, tmax);
        float alpha = __builtin_amdgcn_exp2f(m - mn);
        ll *= alpha;
#pragma unroll
        for (int r = 0; r < 16; r++) {
          acc0[r] *= alpha;
          acc1[r] *= alpha;
        }
        m = mn;
      }
#pragma unroll
      for (int r = 0; r < 16; r++) S[r] = __builtin_amdgcn_exp2f(S[r] - m);
      // tile sum: in-lane tree + one cross-half exchange
      float s8[8];
#pragma unroll
      for (int r = 0; r < 8; r++) s8[r] = S[2 * r] + S[2 * r + 1];
      float rs = ((s8[0] + s8[1]) + (s8[2] + s8[3])) +
                 ((s8[4] + s8[5]) + (s8[6] + s8[7]));
      rs += __shfl_xor(rs, 32);
      ll += rs;
      // pack P to bf16 pairs (scalar casts; compiler fuses) — B dwords direct
      u32x4 pb0v, pb1v;
#pragma unroll
      for (int g = 0; g < 4; g++) {
        unsigned int lo = (unsigned short)f2bf(S[2 * g]);
        unsigned int h16 = (unsigned short)f2bf(S[2 * g + 1]);
        pb0v[g] = lo | (h16 << 16);
      }
#pragma unroll
      for (int g = 0; g < 4; g++) {
        unsigned int lo = (unsigned short)f2bf(S[8 + 2 * g]);
        unsigned int h16 = (unsigned short)f2bf(S[9 + 2 * g]);
        pb1v[g] = lo | (h16 << 16);
      }
      // PV: O^T[d][q] += V^T . P^T (sigma order, lane-local everything)
      s16x8 pb0 = __builtin_bit_cast(s16x8, pb0v);
      s16x8 pb1 = __builtin_bit_cast(s16x8, pb1v);
      acc0 = mfma32(va00, pb0, acc0);
      acc1 = mfma32(va10, pb0, acc1);
      acc0 = mfma32(va01, pb1, acc0);
      acc1 = mfma32(va11, pb1, acc1);
    }

    // ---- combine the 4 per-wave partials (tree merge via LDS) ----
    if (w & 1) {
      float* dst = &XFER[w >> 1][lane][0];
      dst[0] = m; dst[1] = ll;
#pragma unroll
      for (int r = 0; r < 16; r++) { dst[2 + r] = acc0[r]; dst[18 + r] = acc1[r]; }
    }
    __syncthreads();
    if (!(w & 1)) {
      const float* src = &XFER[w >> 1][lane][0];
      float m2 = src[0], l2 = src[1];
      float M = fmaxf(m, m2);
      float a1 = __builtin_amdgcn_exp2f(m - M);
      float a2 = __builtin_amdgcn_exp2f(m2 - M);
      ll = ll * a1 + l2 * a2;
#pragma unroll
      for (int r = 0; r < 16; r++) {
        acc0[r] = acc0[r] * a1 + src[2 + r] * a2;
        acc1[r] = acc1[r] * a1 + src[18 + r] * a2;
      }
      m = M;
    }
    __syncthreads();
    if (w == 2) {
      float* dst = &XFER[0][lane][0];
      dst[0] = m; dst[1] = ll;
#pragma unroll
      for (int r = 0; r < 16; r++) { dst[2 + r] = acc0[r]; dst[18 + r] = acc1[r]; }
    }
    __syncthreads();
    if (w == 0) {
      const float* src = &XFER[0][lane][0];
      float m2 = src[0], l2 = src[1];
      float M = fmaxf(m, m2);
      float a1 = __builtin_amdgcn_exp2f(m - M);
      float a2 = __builtin_amdgcn_exp2f(m2 - M);
      ll = ll * a1 + l2 * a2;
#pragma unroll
      for (int r = 0; r < 16; r++) {
        acc0[r] = acc0[r] * a1 + src[2 + r] * a2;
        acc1[r] = acc1[r] * a1 + src[18 + r] * a2;
      }
      float inv = 1.f / ll;
      size_t rowbase = ((size_t)(b * S_LEN + qb + l32)) * DMODEL + h * HDIM;
#pragma unroll
      for (int g = 0; g < 4; g++) {
        s16x4 o0, o1;
#pragma unroll
        for (int u = 0; u < 4; u++) {
          o0[u] = f2bf(acc0[4 * g + u] * inv);
          o1[u] = f2bf(acc1[4 * g + u] * inv);
        }
        *(s16x4*)&AO[rowbase + 8 * g + 4 * hi] = o0;
        *(s16x4*)&AO[rowbase + 32 + 8 * g + 4 * hi] = o1;
      }
    }
    __syncthreads();  // protect XFER reuse across phases
  }
}

__global__ __launch_bounds__(256, 4) void attn_fwd_kbf16(
    const short* __restrict__ Q, const short* __restrict__ K,
    const short* __restrict__ Vt, short* __restrict__ AO) {
  attn_body<true>(Q, K, Vt, AO);
}
__global__ __launch_bounds__(256, 4) void attn_fwd_kf32(
    const short* __restrict__ Q, const float* __restrict__ K,
    const short* __restrict__ Vt, short* __restrict__ AO) {
  attn_body<false>(Q, K, Vt, AO);
}

extern "C" void kernel_launch(void* const* d_in, const int* in_sizes, int n_in,
                              void* d_out, int out_size, void* d_ws,
                              size_t ws_size, hipStream_t stream) {
  const float* x = (const float*)d_in[0];
  const float* w_qkv = (const float*)d_in[1];
  const float* b_qkv = (const float*)d_in[2];
  const float* w_proj = (const float*)d_in[3];
  const float* b_proj = (const float*)d_in[4];
  float* out = (float*)d_out;
  float* presentK = out + OUT_ELEMS;  // f32 [bh][S][64]

  short* ws = (short*)d_ws;
  const bool kbf16 = ws_size >= (size_t)35651584;  // 17,825,792 shorts

  short *Qw, *Vt, *wprojT, *wqkvT, *attnout, *Kw;
  if (kbf16) {
    Qw = ws;                  // 4,194,304
    Kw = ws + 4194304;        // 4,194,304
    Vt = ws + 8388608;        // 4,194,304
    wprojT = ws + 12582912;   // 1,048,576
    wqkvT = ws + 13631488;    // 3,145,728 (dead after QKV gemm)
    attnout = ws + 13631488;  // 4,194,304 (overlays wqkvT)
  } else {
    if (ws_size < (size_t)27262976) return;
    Qw = ws;
    Vt = ws + 4194304;
    wprojT = ws + 8388608;
    wqkvT = ws + 9437184;
    attnout = ws + 9437184;
    Kw = nullptr;
  }

  transpose_cvt<<<dim3(1536), 256, 0, stream>>>(w_qkv, wqkvT, 1024, 3072);
  transpose_cvt<<<dim3(512), 256, 0, stream>>>(w_proj, wprojT, 1024, 1024);
  // QKV projection: Q(pre-scaled)->Qw, K->presentK f32 (+Kw bf16), V->f32+Vt
  gemm_bt<0, true><<<dim3(24, 32), 256, 0, stream>>>(
      x, wqkvT, b_qkv, Qw, presentK, Vt, Kw, 4096, 3072, 1024);
  // causal attention (paired q-tiles, k-split + combine)
  if (kbf16)
    attn_fwd_kbf16<<<dim3(1024), 256, 0, stream>>>(Qw, Kw, Vt, attnout);
  else
    attn_fwd_kf32<<<dim3(1024), 256, 0, stream>>>(Qw, presentK, Vt, attnout);
  // output projection -> f32 out
  gemm_bt<1, false><<<dim3(8, 32), 256, 0, stream>>>(
      attnout, wprojT, b_proj, nullptr, out, nullptr, nullptr, 4096, 1024,
      1024);
}

// Round 9
// 130.971 us; speedup vs baseline: 1.3888x; 1.1833x over previous
//
#include <hip/hip_runtime.h>
#include <hip/hip_bf16.h>

typedef short s16x8 __attribute__((ext_vector_type(8)));
typedef short s16x4 __attribute__((ext_vector_type(4)));
typedef float f32x4 __attribute__((ext_vector_type(4)));
typedef float f32x16 __attribute__((ext_vector_type(16)));
typedef unsigned int u32x4 __attribute__((ext_vector_type(4)));

#define S_LEN 2048
#define DMODEL 1024
#define NHEAD 16
#define HDIM 64
#define OUT_ELEMS 4194304   // B*S*D
#define HEAD_ELEMS 4194304  // B*H*S*HD
#define SCALE_LOG2 0.1803368801111204f  // 0.125 * log2(e), folded into Q

__device__ inline short f2bf(float f) {
  __hip_bfloat16 h = __float2bfloat16(f);  // RNE
  return __builtin_bit_cast(short, h);
}

__device__ inline f32x4 mfma16(s16x8 a, s16x8 b, f32x4 c) {
  return __builtin_amdgcn_mfma_f32_16x16x32_bf16(a, b, c, 0, 0, 0);
}
__device__ inline f32x16 mfma32(s16x8 a, s16x8 b, f32x16 c) {
  return __builtin_amdgcn_mfma_f32_32x32x16_bf16(a, b, c, 0, 0, 0);
}

// ---- convert+transpose: in [R][C] f32 -> out [C][R] bf16 ----
__global__ __launch_bounds__(256) void transpose_cvt(
    const float* __restrict__ in, short* __restrict__ out, int R, int C) {
  int g = blockIdx.x * 256 + threadIdx.x;
  int c = g % C;
  int r0 = (g / C) * 8;
  s16x8 v;
#pragma unroll
  for (int j = 0; j < 8; j++) v[j] = f2bf(in[(size_t)(r0 + j) * C + c]);
  *(s16x8*)&out[(size_t)c * R + r0] = v;
}

// ---- GEMM: C = A[M,K] * Bt[N,K]^T + bias. (unchanged, proven) ----
template <int MODE, bool AF32>
__global__ __launch_bounds__(256) void gemm_bt(
    const void* __restrict__ Araw, const short* __restrict__ Bt,
    const float* __restrict__ bias, short* __restrict__ Ob0,
    float* __restrict__ Of, short* __restrict__ VtOut,
    short* __restrict__ KwOut, int M, int N, int K) {
  __shared__ short As[128][40];
  __shared__ short Bs[128][40];
  const int t = threadIdx.x;
  const int lane = t & 63;
  const int wid = t >> 6;
  const int wr = wid >> 1, wc = wid & 1;
  const int l16 = lane & 15, lg = lane >> 4;
  const int mbase = blockIdx.y * 128;
  const int nbase = blockIdx.x * 128;

  f32x4 acc[4][4];
#pragma unroll
  for (int m = 0; m < 4; m++)
#pragma unroll
    for (int n = 0; n < 4; n++) acc[m][n] = (f32x4){0.f, 0.f, 0.f, 0.f};

  const int srow = t >> 2;
  const int skc = (t & 3) * 8;

  for (int k0 = 0; k0 < K; k0 += 32) {
    s16x8 a0, a1;
    if constexpr (AF32) {
      const float* Af = (const float*)Araw;
      const float* p0 = &Af[(size_t)(mbase + srow) * K + k0 + skc];
      const float* p1 = &Af[(size_t)(mbase + srow + 64) * K + k0 + skc];
      f32x4 x00 = *(const f32x4*)p0, x01 = *(const f32x4*)(p0 + 4);
      f32x4 x10 = *(const f32x4*)p1, x11 = *(const f32x4*)(p1 + 4);
#pragma unroll
      for (int j = 0; j < 4; j++) {
        a0[j] = f2bf(x00[j]); a0[4 + j] = f2bf(x01[j]);
        a1[j] = f2bf(x10[j]); a1[4 + j] = f2bf(x11[j]);
      }
    } else {
      const short* Ab = (const short*)Araw;
      a0 = *(const s16x8*)&Ab[(size_t)(mbase + srow) * K + k0 + skc];
      a1 = *(const s16x8*)&Ab[(size_t)(mbase + srow + 64) * K + k0 + skc];
    }
    s16x8 b0 = *(const s16x8*)&Bt[(size_t)(nbase + srow) * K + k0 + skc];
    s16x8 b1 = *(const s16x8*)&Bt[(size_t)(nbase + srow + 64) * K + k0 + skc];
    __syncthreads();
    *(s16x8*)&As[srow][skc] = a0;
    *(s16x8*)&As[srow + 64][skc] = a1;
    *(s16x8*)&Bs[srow][skc] = b0;
    *(s16x8*)&Bs[srow + 64][skc] = b1;
    __syncthreads();
    s16x8 af[4], bfr[4];
#pragma unroll
    for (int m = 0; m < 4; m++)
      af[m] = *(const s16x8*)&As[wr * 64 + m * 16 + l16][lg * 8];
#pragma unroll
    for (int n = 0; n < 4; n++)
      bfr[n] = *(const s16x8*)&Bs[wc * 64 + n * 16 + l16][lg * 8];
#pragma unroll
    for (int m = 0; m < 4; m++)
#pragma unroll
      for (int n = 0; n < 4; n++)
        acc[m][n] = mfma16(af[m], bfr[n], acc[m][n]);
  }

#pragma unroll
  for (int m = 0; m < 4; m++) {
#pragma unroll
    for (int n = 0; n < 4; n++) {
      int gcol = nbase + wc * 64 + n * 16 + l16;
      float bv = bias[gcol];
      int part = gcol >> 10;
      int cin = gcol & 1023;
      int h = cin >> 6, hd = cin & 63;
      int grow0 = mbase + wr * 64 + m * 16 + lg * 4;
      float vr[4];
#pragma unroll
      for (int r = 0; r < 4; r++) vr[r] = acc[m][n][r] + bv;
      if (MODE == 0) {
        int bb = grow0 >> 11, s0 = grow0 & 2047;
        size_t base = ((size_t)(bb * NHEAD + h) * S_LEN + s0) * HDIM + hd;
        if (part == 0) {
#pragma unroll
          for (int r = 0; r < 4; r++)
            Ob0[base + (size_t)r * HDIM] = f2bf(vr[r] * SCALE_LOG2);
        } else if (part == 1) {
#pragma unroll
          for (int r = 0; r < 4; r++) Of[base + (size_t)r * HDIM] = vr[r];
          if (KwOut) {
#pragma unroll
            for (int r = 0; r < 4; r++)
              KwOut[base + (size_t)r * HDIM] = f2bf(vr[r]);
          }
        } else {
#pragma unroll
          for (int r = 0; r < 4; r++)
            Of[HEAD_ELEMS + base + (size_t)r * HDIM] = vr[r];
          s16x4 pk;
#pragma unroll
          for (int r = 0; r < 4; r++) pk[r] = f2bf(vr[r]);
          // sigma-permuted key position (runs of 4 preserved)
          int w32 = s0 & 31;
          int nw = ((w32 >> 4) << 4) | ((w32 & 4) << 1) | ((w32 & 8) >> 1);
          int sperm = (s0 & ~31) | nw;
          *(s16x4*)&VtOut[((size_t)(bb * NHEAD + h) * HDIM + hd) * S_LEN +
                          sperm] = pk;
        }
      } else {
#pragma unroll
        for (int r = 0; r < 4; r++) Of[(size_t)(grow0 + r) * N + gcol] = vr[r];
      }
    }
  }
}

// ==== NEW attention: block = 128 q-rows (4 waves x 32q), KVBLK=64 shared ====
// K, Vt staged coalesced into XOR-swizzled LDS (double-buffered, T14 split).
// LDS(row, chunk) holds global chunk (chunk ^ (row&7)); readers re-XOR.
__global__ __launch_bounds__(256, 2) void attn_fwd_kbf16(
    const short* __restrict__ Q, const short* __restrict__ K,
    const short* __restrict__ Vt, short* __restrict__ AO) {
  __shared__ short Ks[2][64][64];
  __shared__ short Vs[2][64][64];

  const int p = blockIdx.x;            // 512 blocks
  const int bh = p & 31;               // bh%8 pins XCD residue
  const int seg = (p >> 5) & 7;
  const int qi = (p < 256) ? (15 - seg) : seg;  // p,p+256 same CU: qi sums 15
  const int qb = qi * 128;
  const int nt = 2 * qi + 2;           // 64-key tiles

  const int tid = threadIdx.x;
  const int w = tid >> 6;
  const int lane = tid & 63;
  const int l32 = lane & 31;
  const int hi = lane >> 5;
  const int rsub = lane >> 3;          // 0..7
  const int sub = lane & 7;            // 16B chunk within 128B row

  const short* Qb = Q + (size_t)bh * (S_LEN * HDIM);
  const short* Kb = K + (size_t)bh * (S_LEN * HDIM);
  const short* Vb = Vt + (size_t)bh * (HDIM * S_LEN);
  const int b = bh >> 4, h = bh & 15;

  const int qrow = qb + 32 * w + l32;  // this lane's q (col index)
  const int qminw = qb + 32 * w;
  const int qmaxw = qminw + 31;

  s16x8 qf[4];
#pragma unroll
  for (int c = 0; c < 4; c++)
    qf[c] = *(const s16x8*)&Qb[(size_t)qrow * HDIM + c * 16 + hi * 8];

  f32x16 acc0 = {0.f}, acc1 = {0.f};
  float m = -1e30f, ll = 0.f;

  s16x8 kreg[2], vreg[2];
  auto LOADT = [&](int kt) {
    const int kb = kt * 64;
#pragma unroll
    for (int c = 0; c < 2; c++) {
      int row = 16 * w + 8 * c + rsub;
      int gs = sub ^ (row & 7);  // inverse swizzle on global source
      kreg[c] = *(const s16x8*)&Kb[(size_t)(kb + row) * HDIM + gs * 8];
      vreg[c] = *(const s16x8*)&Vb[(size_t)row * S_LEN + kb + gs * 8];
    }
  };
  auto WRITET = [&](int bb) {
#pragma unroll
    for (int c = 0; c < 2; c++) {
      int row = 16 * w + 8 * c + rsub;
      *(s16x8*)&Ks[bb][row][sub * 8] = kreg[c];
      *(s16x8*)&Vs[bb][row][sub * 8] = vreg[c];
    }
  };

  LOADT(0);
  WRITET(0);
  __syncthreads();
  int cur = 0;

#pragma unroll 1
  for (int kt = 0; kt < nt; kt++) {
    const int kb = kt * 64;
    if (kt + 1 < nt) LOADT(kt + 1);  // issue early: hides under compute
    if (kb <= qmaxw) {
      // ---- QK^T: S^T[key][q] over two 32-key halves ----
      f32x16 S0 = {0.f}, S1 = {0.f};
#pragma unroll
      for (int c = 0; c < 4; c++) {
        int cs = c * 2 + hi;
        int r0 = l32;
        int r1 = 32 + l32;
        s16x8 k0 = *(const s16x8*)&Ks[cur][r0][(cs ^ (r0 & 7)) * 8];
        s16x8 k1 = *(const s16x8*)&Ks[cur][r1][(cs ^ (r1 & 7)) * 8];
        S0 = mfma32(k0, qf[c], S0);
        S1 = mfma32(k1, qf[c], S1);
      }
      // causal mask (only tiles overlapping the wave's diagonal)
      if (kb + 63 > qminw) {
#pragma unroll
        for (int r = 0; r < 16; r++) {
          int key0 = kb + (r & 3) + 8 * (r >> 2) + 4 * hi;
          S0[r] = (key0 <= qrow) ? S0[r] : -1e30f;
          S1[r] = (key0 + 32 <= qrow) ? S1[r] : -1e30f;
        }
      }
      // tile max (tree over 32 + cross-half)
      float t8[8];
#pragma unroll
      for (int r = 0; r < 8; r++)
        t8[r] = fmaxf(fmaxf(S0[2 * r], S0[2 * r + 1]),
                      fmaxf(S1[2 * r], S1[2 * r + 1]));
      float tmax = fmaxf(fmaxf(fmaxf(t8[0], t8[1]), fmaxf(t8[2], t8[3])),
                         fmaxf(fmaxf(t8[4], t8[5]), fmaxf(t8[6], t8[7])));
      tmax = fmaxf(tmax, __shfl_xor(tmax, 32));
      // defer-max rescale
      if (!__all(tmax <= m + 11.0f)) {
        float mn = fmaxf(m, tmax);
        float alpha = __builtin_amdgcn_exp2f(m - mn);
        ll *= alpha;
#pragma unroll
        for (int r = 0; r < 16; r++) {
          acc0[r] *= alpha;
          acc1[r] *= alpha;
        }
        m = mn;
      }
#pragma unroll
      for (int r = 0; r < 16; r++) {
        S0[r] = __builtin_amdgcn_exp2f(S0[r] - m);
        S1[r] = __builtin_amdgcn_exp2f(S1[r] - m);
      }
      // tile sum
      float s8[8];
#pragma unroll
      for (int r = 0; r < 8; r++)
        s8[r] = (S0[2 * r] + S0[2 * r + 1]) + (S1[2 * r] + S1[2 * r + 1]);
      float rs = ((s8[0] + s8[1]) + (s8[2] + s8[3])) +
                 ((s8[4] + s8[5]) + (s8[6] + s8[7]));
      rs += __shfl_xor(rs, 32);
      ll += rs;
      // ---- pack P + PV (sigma order: lane-local, LDS-swizzled V^T) ----
#pragma unroll
      for (int half = 0; half < 2; half++) {
        const f32x16& S = half ? S1 : S0;
        u32x4 pbAv, pbBv;
#pragma unroll
        for (int g = 0; g < 4; g++) {
          unsigned int lo = (unsigned short)f2bf(S[2 * g]);
          unsigned int h16 = (unsigned short)f2bf(S[2 * g + 1]);
          pbAv[g] = lo | (h16 << 16);
          unsigned int lo2 = (unsigned short)f2bf(S[8 + 2 * g]);
          unsigned int h162 = (unsigned short)f2bf(S[9 + 2 * g]);
          pbBv[g] = lo2 | (h162 << 16);
        }
#pragma unroll
        for (int gg = 0; gg < 2; gg++) {
          s16x8 pb = __builtin_bit_cast(s16x8, gg ? pbBv : pbAv);
          int cs = (half * 2 + gg) * 2 + hi;
          int v0r = l32;
          int v1r = 32 + l32;
          s16x8 va0 = *(const s16x8*)&Vs[cur][v0r][(cs ^ (v0r & 7)) * 8];
          s16x8 va1 = *(const s16x8*)&Vs[cur][v1r][(cs ^ (v1r & 7)) * 8];
          acc0 = mfma32(va0, pb, acc0);
          acc1 = mfma32(va1, pb, acc1);
        }
      }
    }
    if (kt + 1 < nt) WRITET(cur ^ 1);  // after compute; 1 barrier/trip
    __syncthreads();
    cur ^= 1;
  }

  // ---- epilogue: each lane owns q-row qrow fully ----
  float inv = 1.f / ll;
  size_t rowbase = ((size_t)(b * S_LEN + qrow)) * DMODEL + h * HDIM;
#pragma unroll
  for (int g = 0; g < 4; g++) {
    s16x4 o0, o1;
#pragma unroll
    for (int u = 0; u < 4; u++) {
      o0[u] = f2bf(acc0[4 * g + u] * inv);
      o1[u] = f2bf(acc1[4 * g + u] * inv);
    }
    *(s16x4*)&AO[rowbase + 8 * g + 4 * hi] = o0;
    *(s16x4*)&AO[rowbase + 32 + 8 * g + 4 * hi] = o1;
  }
}

// ---- fallback (ws too small): round-8 proven k-split kernel, f32 K ----
__global__ __launch_bounds__(256, 4) void attn_fwd_kf32(
    const short* __restrict__ Q, const float* __restrict__ Kraw,
    const short* __restrict__ Vt, short* __restrict__ AO) {
  __shared__ float XFER[2][64][37];
  const int p = blockIdx.x;
  const int xcd = p & 7;
  const int rank = p >> 3;
  const int bh = (xcd << 2) | (rank >> 5);
  const int pr = rank & 31;
  const int tid = threadIdx.x;
  const int w = tid >> 6;
  const int lane = tid & 63;
  const int l32 = lane & 31;
  const int hi = lane >> 5;
  const short* Qb = Q + (size_t)bh * (S_LEN * HDIM);
  const short* Vb = Vt + (size_t)bh * (HDIM * S_LEN);
  const float* Kb32 = Kraw + (size_t)bh * (S_LEN * HDIM);
  const int b = bh >> 4, h = bh & 15;

#pragma unroll 1
  for (int ph = 0; ph < 2; ph++) {
    const int j = ph ? pr : 63 - pr;
    const int qb = j * 32;
    s16x8 qf[4];
#pragma unroll
    for (int c = 0; c < 4; c++)
      qf[c] = *(const s16x8*)&Qb[(size_t)(qb + l32) * HDIM + c * 16 + hi * 8];
    f32x16 acc0 = {0.f}, acc1 = {0.f};
    float m = -1e30f, ll = 0.f;
#pragma unroll 1
    for (int kt = w; kt <= j; kt += 4) {
      const int kb = kt * 32;
      f32x16 S = {0.f};
#pragma unroll
      for (int c = 0; c < 4; c++) {
        const float* kr = &Kb32[(size_t)(kb + l32) * HDIM + c * 16 + hi * 8];
        f32x4 k0 = *(const f32x4*)kr, k1 = *(const f32x4*)(kr + 4);
        s16x8 kf;
#pragma unroll
        for (int u = 0; u < 4; u++) {
          kf[u] = f2bf(k0[u]);
          kf[4 + u] = f2bf(k1[u]);
        }
        S = mfma32(kf, qf[c], S);
      }
      const short* vr0 = &Vb[(size_t)l32 * S_LEN + kb + hi * 8];
      const short* vr1 = &Vb[(size_t)(32 + l32) * S_LEN + kb + hi * 8];
      s16x8 va00 = *(const s16x8*)vr0;
      s16x8 va01 = *(const s16x8*)(vr0 + 16);
      s16x8 va10 = *(const s16x8*)vr1;
      s16x8 va11 = *(const s16x8*)(vr1 + 16);
      if (kt == j) {
#pragma unroll
        for (int r = 0; r < 16; r++) {
          int keyl = (r & 3) + 8 * (r >> 2) + 4 * hi;
          S[r] = (keyl <= l32) ? S[r] : -1e30f;
        }
      }
      float t8[8];
#pragma unroll
      for (int r = 0; r < 8; r++) t8[r] = fmaxf(S[2 * r], S[2 * r + 1]);
      float tmax = fmaxf(fmaxf(fmaxf(t8[0], t8[1]), fmaxf(t8[2], t8[3])),
                         fmaxf(fmaxf(t8[4], t8[5]), fmaxf(t8[6], t8[7])));
      tmax = fmaxf(tmax, __shfl_xor(tmax, 32));
      if (!__all(tmax <= m + 11.0f)) {
        float mn = fmaxf(m, tmax);
        float alpha = __builtin_amdgcn_exp2f(m - mn);
        ll *= alpha;
#pragma unroll
        for (int r = 0; r < 16; r++) {
          acc0[r] *= alpha;
          acc1[r] *= alpha;
        }
        m = mn;
      }
#pragma unroll
      for (int r = 0; r < 16; r++) S[r] = __builtin_amdgcn_exp2f(S[r] - m);
      float s8[8];
#pragma unroll
      for (int r = 0; r < 8; r++) s8[r] = S[2 * r] + S[2 * r + 1];
      float rs = ((s8[0] + s8[1]) + (s8[2] + s8[3])) +
                 ((s8[4] + s8[5]) + (s8[6] + s8[7]));
      rs += __shfl_xor(rs, 32);
      ll += rs;
      u32x4 pb0v, pb1v;
#pragma unroll
      for (int g = 0; g < 4; g++) {
        unsigned int lo = (unsigned short)f2bf(S[2 * g]);
        unsigned int h16 = (unsigned short)f2bf(S[2 * g + 1]);
        pb0v[g] = lo | (h16 << 16);
        unsigned int lo2 = (unsigned short)f2bf(S[8 + 2 * g]);
        unsigned int h162 = (unsigned short)f2bf(S[9 + 2 * g]);
        pb1v[g] = lo2 | (h162 << 16);
      }
      s16x8 pb0 = __builtin_bit_cast(s16x8, pb0v);
      s16x8 pb1 = __builtin_bit_cast(s16x8, pb1v);
      acc0 = mfma32(va00, pb0, acc0);
      acc1 = mfma32(va10, pb0, acc1);
      acc0 = mfma32(va01, pb1, acc0);
      acc1 = mfma32(va11, pb1, acc1);
    }
    if (w & 1) {
      float* dst = &XFER[w >> 1][lane][0];
      dst[0] = m; dst[1] = ll;
#pragma unroll
      for (int r = 0; r < 16; r++) { dst[2 + r] = acc0[r]; dst[18 + r] = acc1[r]; }
    }
    __syncthreads();
    if (!(w & 1)) {
      const float* src = &XFER[w >> 1][lane][0];
      float m2 = src[0], l2 = src[1];
      float M = fmaxf(m, m2);
      float a1 = __builtin_amdgcn_exp2f(m - M);
      float a2 = __builtin_amdgcn_exp2f(m2 - M);
      ll = ll * a1 + l2 * a2;
#pragma unroll
      for (int r = 0; r < 16; r++) {
        acc0[r] = acc0[r] * a1 + src[2 + r] * a2;
        acc1[r] = acc1[r] * a1 + src[18 + r] * a2;
      }
      m = M;
    }
    __syncthreads();
    if (w == 2) {
      float* dst = &XFER[0][lane][0];
      dst[0] = m; dst[1] = ll;
#pragma unroll
      for (int r = 0; r < 16; r++) { dst[2 + r] = acc0[r]; dst[18 + r] = acc1[r]; }
    }
    __syncthreads();
    if (w == 0) {
      const float* src = &XFER[0][lane][0];
      float m2 = src[0], l2 = src[1];
      float M = fmaxf(m, m2);
      float a1 = __builtin_amdgcn_exp2f(m - M);
      float a2 = __builtin_amdgcn_exp2f(m2 - M);
      ll = ll * a1 + l2 * a2;
#pragma unroll
      for (int r = 0; r < 16; r++) {
        acc0[r] = acc0[r] * a1 + src[2 + r] * a2;
        acc1[r] = acc1[r] * a1 + src[18 + r] * a2;
      }
      float inv = 1.f / ll;
      size_t rowbase = ((size_t)(b * S_LEN + qb + l32)) * DMODEL + h * HDIM;
#pragma unroll
      for (int g = 0; g < 4; g++) {
        s16x4 o0, o1;
#pragma unroll
        for (int u = 0; u < 4; u++) {
          o0[u] = f2bf(acc0[4 * g + u] * inv);
          o1[u] = f2bf(acc1[4 * g + u] * inv);
        }
        *(s16x4*)&AO[rowbase + 8 * g + 4 * hi] = o0;
        *(s16x4*)&AO[rowbase + 32 + 8 * g + 4 * hi] = o1;
      }
    }
    __syncthreads();
  }
}

extern "C" void kernel_launch(void* const* d_in, const int* in_sizes, int n_in,
                              void* d_out, int out_size, void* d_ws,
                              size_t ws_size, hipStream_t stream) {
  const float* x = (const float*)d_in[0];
  const float* w_qkv = (const float*)d_in[1];
  const float* b_qkv = (const float*)d_in[2];
  const float* w_proj = (const float*)d_in[3];
  const float* b_proj = (const float*)d_in[4];
  float* out = (float*)d_out;
  float* presentK = out + OUT_ELEMS;  // f32 [bh][S][64]

  short* ws = (short*)d_ws;
  const bool kbf16 = ws_size >= (size_t)35651584;  // 17,825,792 shorts

  short *Qw, *Vt, *wprojT, *wqkvT, *attnout, *Kw;
  if (kbf16) {
    Qw = ws;                  // 4,194,304
    Kw = ws + 4194304;        // 4,194,304
    Vt = ws + 8388608;        // 4,194,304
    wprojT = ws + 12582912;   // 1,048,576
    wqkvT = ws + 13631488;    // 3,145,728 (dead after QKV gemm)
    attnout = ws + 13631488;  // 4,194,304 (overlays wqkvT)
  } else {
    if (ws_size < (size_t)27262976) return;
    Qw = ws;
    Vt = ws + 4194304;
    wprojT = ws + 8388608;
    wqkvT = ws + 9437184;
    attnout = ws + 9437184;
    Kw = nullptr;
  }

  transpose_cvt<<<dim3(1536), 256, 0, stream>>>(w_qkv, wqkvT, 1024, 3072);
  transpose_cvt<<<dim3(512), 256, 0, stream>>>(w_proj, wprojT, 1024, 1024);
  // QKV projection: Q(pre-scaled)->Qw, K->presentK f32 (+Kw bf16), V->f32+Vt
  gemm_bt<0, true><<<dim3(24, 32), 256, 0, stream>>>(
      x, wqkvT, b_qkv, Qw, presentK, Vt, Kw, 4096, 3072, 1024);
  // causal attention
  if (kbf16)
    attn_fwd_kbf16<<<dim3(512), 256, 0, stream>>>(Qw, Kw, Vt, attnout);
  else
    attn_fwd_kf32<<<dim3(1024), 256, 0, stream>>>(Qw, presentK, Vt, attnout);
  // output projection -> f32 out
  gemm_bt<1, false><<<dim3(8, 32), 256, 0, stream>>>(
      attnout, wprojT, b_proj, nullptr, out, nullptr, nullptr, 4096, 1024,
      1024);
}